// Round 21
// baseline (83.529 us; speedup 1.0000x reference)
//
#include <hip/hip_runtime.h>

// Point-splat renderer, round 21: TILE-MAJOR binning pipeline.
//
//  Measured cost law (R13-R19): paint time ~ scattered-run count x 64B line;
//  block-major regions fragment each tile into NB sub-segments (NB=1024 ->
//  56-87MB fetch, 40us). Fix: global (tile,block) scan -> scatter writes a
//  tile-major bins array; paint reads each tile's ~3900 entries in ONE dense
//  coalesced sweep (16MB).
//
//  1. hist (1024x512):  project once (float4x3), write pixArr (coalesced
//     uint4) + LDS histogram -> histB[b*NT+t] (coalesced 4KB/block).
//  2. scanA (1024 blks): per tile t, exclusive scan over b of histB[b][t]
//     (strided reads, 16x line reuse) -> prefT[t*NB+b] (coalesced) + total[t].
//  3. scanB (1 blk):     exclusive scan of total -> tileBase[t].
//  4. scatter (1024x512): re-read pixArr; LDS cursors seeded
//     tileBase[t]+prefT[t][b]; store (lp<<22|idx) tile-major. Sub-segment
//     boundary sectors merge by byte-mask (validated R13 histG columns).
//  5. paint (1024x256):  dense read [tileBase[t],tileBase[t+1]) -> LDS
//     atomicMax(idx+1) -> color gather -> CHW store. No runs, no sentinels.
//
//  winner = max index is order-free -> deterministic despite racy slot order.
//
// Inputs: d_in[0] positions (N*3 f32), d_in[1] colors (N*3 f32),
//         d_in[2] camera_pose (16 f32), d_in[3] intrinsics (9 f32),
//         d_in[4] H (1 int), d_in[5] W (1 int)
// Output: (1,3,H,W) f32 flat.

#define NB    1024             // point blocks
#define TB    512              // threads (hist & scatter)
#define NT    1024             // 32x32 grid of 32x32-px tiles
#define IMGW  1024
#define IMGHW (1024 * 1024)

__global__ void __launch_bounds__(TB)
hist_kernel(const float* __restrict__ pos,
            const float* __restrict__ pose,
            const float* __restrict__ intr,
            unsigned* __restrict__ pixArr,
            unsigned* __restrict__ histB,
            int n, int ppb) {
    __shared__ unsigned h[NT];
    int tid = threadIdx.x;
    for (int t = tid; t < NT; t += TB) h[t] = 0;
    __syncthreads();

    float r00 = pose[0], r01 = pose[1], r02 = pose[2],  t0 = pose[3];
    float r10 = pose[4], r11 = pose[5], r12 = pose[6],  t1 = pose[7];
    float r20 = pose[8], r21 = pose[9], r22 = pose[10], t2 = pose[11];
    float fx = intr[0], cx = intr[2];
    float fy = intr[4], cy = intr[5];

    int start = blockIdx.x * ppb;            // ppb, start multiples of 4
    int cnt = min(start + ppb, n) - start;   // multiple of 4
    if (cnt < 0) cnt = 0;

    const float4* p4 = (const float4*)(pos + (size_t)3 * (size_t)start);
    uint4* pa4 = (uint4*)(pixArr + start);
    for (int j4 = tid * 4; j4 < cnt; j4 += TB * 4) {
        int g = j4 >> 2;
        float4 A = p4[3 * g + 0];
        float4 B = p4[3 * g + 1];
        float4 C = p4[3 * g + 2];
        float xs0 = A.x, ys0 = A.y, zs0 = A.z;
        float xs1 = A.w, ys1 = B.x, zs1 = B.y;
        float xs2 = B.z, ys2 = B.w, zs2 = C.x;
        float xs3 = C.y, ys3 = C.z, zs3 = C.w;

        unsigned pv[4];
        #define PROJ(K, PX, PY, PZ)                                          \
        {                                                                    \
            float x = r00 * PX + r01 * PY + r02 * PZ + t0;                   \
            float y = r10 * PX + r11 * PY + r12 * PZ + t1;                   \
            float z = r20 * PX + r21 * PY + r22 * PZ + t2;                   \
            float u = fx * x / z + cx;                                       \
            float v = fy * y / z + cy;                                       \
            int xi = (int)u;   /* trunc == numpy astype(int32) */            \
            int yi = (int)v;                                                 \
            unsigned p = 0xFFFFFFFFu;                                        \
            if (xi >= 0 && xi < IMGW && yi >= 0 && yi < IMGW) {              \
                p = ((unsigned)yi << 10) | (unsigned)xi;                     \
                int tt = ((yi >> 5) << 5) + (xi >> 5);                       \
                atomicAdd(&h[tt], 1u);                                       \
            }                                                                \
            pv[K] = p;                                                       \
        }
        PROJ(0, xs0, ys0, zs0)
        PROJ(1, xs1, ys1, zs1)
        PROJ(2, xs2, ys2, zs2)
        PROJ(3, xs3, ys3, zs3)
        #undef PROJ

        pa4[g] = make_uint4(pv[0], pv[1], pv[2], pv[3]);
    }
    __syncthreads();

    // coalesced: histB[b*NT + t]
    unsigned* hb = histB + (size_t)blockIdx.x * NT;
    for (int t = tid; t < NT; t += TB) hb[t] = h[t];
}

// per-tile exclusive scan over the 1024 block counts
__global__ void __launch_bounds__(256)
scanA_kernel(const unsigned* __restrict__ histB,
             unsigned* __restrict__ prefT,
             unsigned* __restrict__ total) {
    __shared__ unsigned sc[256];
    int t = blockIdx.x;
    int tid = threadIdx.x;

    // thread owns blocks b = 4tid..4tid+3 (strided reads, 16x line reuse)
    unsigned c0 = histB[(size_t)(4 * tid + 0) * NT + t];
    unsigned c1 = histB[(size_t)(4 * tid + 1) * NT + t];
    unsigned c2 = histB[(size_t)(4 * tid + 2) * NT + t];
    unsigned c3 = histB[(size_t)(4 * tid + 3) * NT + t];
    unsigned s = c0 + c1 + c2 + c3;

    unsigned v = s;
    sc[tid] = v;
    __syncthreads();
    for (int off = 1; off < 256; off <<= 1) {
        unsigned add = (tid >= off) ? sc[tid - off] : 0u;
        __syncthreads();
        v += add;
        sc[tid] = v;
        __syncthreads();
    }
    unsigned excl = v - s;

    unsigned* pt = prefT + (size_t)t * NB + 4 * tid;    // coalesced
    pt[0] = excl;
    pt[1] = excl + c0;
    pt[2] = excl + c0 + c1;
    pt[3] = excl + c0 + c1 + c2;
    if (tid == 255) total[t] = v;                       // tile total
}

__global__ void __launch_bounds__(NT)
scanB_kernel(const unsigned* __restrict__ total,
             unsigned* __restrict__ tileBase) {
    __shared__ unsigned sc[NT];
    int t = threadIdx.x;
    unsigned x = total[t];
    unsigned v = x;
    sc[t] = v;
    __syncthreads();
    for (int off = 1; off < NT; off <<= 1) {
        unsigned add = (t >= off) ? sc[t - off] : 0u;
        __syncthreads();
        v += add;
        sc[t] = v;
        __syncthreads();
    }
    tileBase[t] = v - x;
    if (t == NT - 1) tileBase[NT] = v;
}

__global__ void __launch_bounds__(TB)
scatter_kernel(const unsigned* __restrict__ pixArr,
               const unsigned* __restrict__ prefT,
               const unsigned* __restrict__ tileBase,
               unsigned* __restrict__ binsT,
               int n, int ppb) {
    __shared__ unsigned cur[NT];
    int tid = threadIdx.x;
    int b = blockIdx.x;
    for (int t = tid; t < NT; t += TB)
        cur[t] = tileBase[t] + prefT[(size_t)t * NB + b];
    __syncthreads();

    int start = b * ppb;
    int cnt = min(start + ppb, n) - start;
    if (cnt < 0) cnt = 0;

    const uint4* pa4 = (const uint4*)(pixArr + start);
    for (int j4 = tid * 4; j4 < cnt; j4 += TB * 4) {
        uint4 q = pa4[j4 >> 2];
        unsigned pvs[4] = {q.x, q.y, q.z, q.w};
        #pragma unroll
        for (int k = 0; k < 4; ++k) {
            unsigned pv = pvs[k];
            if (pv == 0xFFFFFFFFu) continue;
            unsigned xi = pv & 1023u, yi = pv >> 10;
            unsigned t  = ((yi >> 5) << 5) + (xi >> 5);
            unsigned lp = ((yi & 31u) << 5) + (xi & 31u);
            unsigned slot = atomicAdd(&cur[t], 1u);     // LDS
            binsT[slot] = (lp << 22) | (unsigned)(start + j4 + k);
        }
    }
}

__global__ void __launch_bounds__(256)
paint_kernel(const unsigned* __restrict__ binsT,
             const unsigned* __restrict__ tileBase,
             const float* __restrict__ colors,
             float* __restrict__ out) {
    __shared__ unsigned win[NT];    // winner idx+1 per local pixel
    int t = blockIdx.x;
    int tid = threadIdx.x;
    #pragma unroll
    for (int l = tid; l < NT; l += 256) win[l] = 0;
    __syncthreads();

    unsigned s0 = tileBase[t], s1 = tileBase[t + 1];
    for (unsigned k = s0 + tid; k < s1; k += 256) {     // dense, coalesced
        unsigned e = binsT[k];
        atomicMax(&win[e >> 22], (e & 0x3FFFFFu) + 1u); // LDS
    }
    __syncthreads();

    int tx = (t & 31) << 5, ty = (t >> 5) << 5;
    for (int l = tid; l < NT; l += 256) {
        unsigned w = win[l];
        float r = 0.0f, g = 0.0f, bl = 0.0f;
        if (w) {
            unsigned wi = w - 1u;
            r  = fminf(fmaxf(colors[3 * wi + 0], 0.0f), 1.0f);
            g  = fminf(fmaxf(colors[3 * wi + 1], 0.0f), 1.0f);
            bl = fminf(fmaxf(colors[3 * wi + 2], 0.0f), 1.0f);
        }
        int x = tx + (l & 31), y = ty + (l >> 5);
        int p = y * IMGW + x;
        out[p] = r;
        out[IMGHW + p] = g;
        out[2 * IMGHW + p] = bl;
    }
}

// ---------- fallback: memset + single atomic pass + paint ----------

__global__ void proj_simple(const float* __restrict__ pos,
                            const float* __restrict__ pose,
                            const float* __restrict__ intr,
                            const int* __restrict__ Hp,
                            const int* __restrict__ Wp,
                            int* __restrict__ winner, int n) {
    int i = blockIdx.x * blockDim.x + threadIdx.x;
    if (i >= n) return;
    float px = pos[3 * i], py = pos[3 * i + 1], pz = pos[3 * i + 2];
    float x = pose[0] * px + pose[1] * py + pose[2]  * pz + pose[3];
    float y = pose[4] * px + pose[5] * py + pose[6]  * pz + pose[7];
    float z = pose[8] * px + pose[9] * py + pose[10] * pz + pose[11];
    float u = intr[0] * x / z + intr[2];
    float v = intr[4] * y / z + intr[5];
    int xi = (int)u, yi = (int)v;
    int W = *Wp, H = *Hp;
    if (xi >= 0 && xi < W && yi >= 0 && yi < H) atomicMax(&winner[yi * W + xi], i);
}

__global__ void paint_simple(const int* __restrict__ winner,
                             const float* __restrict__ colors,
                             float* __restrict__ out, int HW) {
    int p = blockIdx.x * blockDim.x + threadIdx.x;
    if (p >= HW) return;
    int w = winner[p];
    float r = 0.0f, g = 0.0f, b = 0.0f;
    if (w >= 0) {
        r = fminf(fmaxf(colors[3 * w + 0], 0.0f), 1.0f);
        g = fminf(fmaxf(colors[3 * w + 1], 0.0f), 1.0f);
        b = fminf(fmaxf(colors[3 * w + 2], 0.0f), 1.0f);
    }
    out[p] = r; out[HW + p] = g; out[2 * HW + p] = b;
}

extern "C" void kernel_launch(void* const* d_in, const int* in_sizes, int n_in,
                              void* d_out, int out_size, void* d_ws, size_t ws_size,
                              hipStream_t stream) {
    const float* positions = (const float*)d_in[0];
    const float* colors    = (const float*)d_in[1];
    const float* pose      = (const float*)d_in[2];
    const float* intr      = (const float*)d_in[3];
    const int*   Hp        = (const int*)d_in[4];
    const int*   Wp        = (const int*)d_in[5];
    float* out = (float*)d_out;

    int n  = in_sizes[0] / 3;       // number of points
    int HW = out_size / 3;          // H*W pixels

    int ppb = ((n + NB - 1) / NB + 3) & ~3;             // multiple of 4

    unsigned* pixArr   = (unsigned*)d_ws;                       // n
    unsigned* binsT    = pixArr + n;                            // n
    unsigned* histB    = binsT + n;                             // NB*NT
    unsigned* prefT    = histB + (size_t)NB * NT;               // NT*NB
    unsigned* total    = prefT + (size_t)NT * NB;               // NT
    unsigned* tileBase = total + NT;                            // NT+1
    size_t needFast = ((size_t)2 * n + 2 * (size_t)NB * NT + 2 * NT + 1)
                      * sizeof(unsigned);

    bool fast = (HW == IMGHW) && (n >= 4096) && ((n & 3) == 0) &&
                (n <= 4000000) && (ws_size >= needFast);

    if (fast) {
        hist_kernel<<<NB, TB, 0, stream>>>(positions, pose, intr,
                                           pixArr, histB, n, ppb);
        scanA_kernel<<<NT, 256, 0, stream>>>(histB, prefT, total);
        scanB_kernel<<<1, NT, 0, stream>>>(total, tileBase);
        scatter_kernel<<<NB, TB, 0, stream>>>(pixArr, prefT, tileBase,
                                              binsT, n, ppb);
        paint_kernel<<<NT, 256, 0, stream>>>(binsT, tileBase, colors, out);
        return;
    }

    // ---- fallback ----
    int* winner = (int*)d_ws;
    const int block = 256;
    hipMemsetAsync(winner, 0xFF, (size_t)HW * sizeof(int), stream);
    int grid = (n + block - 1) / block;
    proj_simple<<<grid, block, 0, stream>>>(positions, pose, intr, Hp, Wp,
                                            winner, n);
    int grid2 = (HW + block - 1) / block;
    paint_simple<<<grid2, block, 0, stream>>>(winner, colors, out, HW);
}

// Round 22
// 63.451 us; speedup vs baseline: 1.3164x; 1.3164x over previous
//
#include <hip/hip_runtime.h>

// Point-splat renderer, round 22: best-of-measured halves.
//   binsort: NB=512 x TB=512, DENSE regions, float4x3 loads.
//     (align8 cost ~16us write-amp: R14 dense 25us vs R16 align8 41us;
//      TB=1024 capped occ at 50% in R15; NB=512/TB=512 dense = 45KB LDS ->
//      3 blk/CU, 75% wave capacity.)
//   paint: R13's thread-per-run, NT=1024 tile-blocks x 512 thr (4 blk/CU,
//     imbalance hidden by oversubscription). Run count 512K (NB=512) is the
//     measured paint cost law: fetch ~ runs x line -> ~20us dense.
//   No winner array, no fill: 2 dispatches total.
//
//  Kernel 1 (binsort): project 4 pts/iter (float4x3) -> LDS stash + LDS
//  1024-tile histogram; exclusive scan of RAW counts (dense); publish
//  (base<<16|count) to histG[t*NB+b] (tile-major: strided 4B writes merge
//  by byte-mask; paint reads coalesced); replay stash through LDS cursors
//  -> dense (lp<<22|idx) stores into the block's private region.
//  Kernel 2 (paint): block t; thread tid walks run (region tid, tile t)
//  exactly count entries; LDS atomicMax(idx+1); gather colors; CHW store.
//  winner = max index is order-free -> deterministic.
//
// Inputs: d_in[0] positions (N*3 f32), d_in[1] colors (N*3 f32),
//         d_in[2] camera_pose (16 f32), d_in[3] intrinsics (9 f32),
//         d_in[4] H (1 int), d_in[5] W (1 int)
// Output: (1,3,H,W) f32 flat.

#define NB      512            // binsort blocks / regions
#define TB      512            // threads per block (binsort & paint)
#define NT      1024           // 32x32 grid of 32x32-px tiles
#define PPB_MAX 7936           // stash capacity (LDS words)
#define IMGW    1024
#define IMGHW   (1024 * 1024)

__host__ __device__ __forceinline__ unsigned align8u(unsigned x) {
    return (x + 7u) & ~7u;
}

__global__ void __launch_bounds__(TB)
binsort_kernel(const float* __restrict__ pos,
               const float* __restrict__ pose,
               const float* __restrict__ intr,
               unsigned* __restrict__ bins,
               unsigned* __restrict__ histG,
               int n, int ppb, int region) {
    __shared__ unsigned stash[PPB_MAX];
    __shared__ unsigned h[NT];
    __shared__ unsigned base_[NT];
    __shared__ unsigned cur[NT];
    __shared__ unsigned sc[TB];

    int tid = threadIdx.x;
    for (int t = tid; t < NT; t += TB) h[t] = 0;
    __syncthreads();

    float r00 = pose[0], r01 = pose[1], r02 = pose[2],  t0 = pose[3];
    float r10 = pose[4], r11 = pose[5], r12 = pose[6],  t1 = pose[7];
    float r20 = pose[8], r21 = pose[9], r22 = pose[10], t2 = pose[11];
    float fx = intr[0], cx = intr[2];
    float fy = intr[4], cy = intr[5];

    int start = blockIdx.x * ppb;            // ppb multiple of 4
    int cnt = min(start + ppb, n) - start;   // multiple of 4 (n mult 4)
    if (cnt < 0) cnt = 0;

    // ---- pass 1: project 4 points/iter (float4 x3), stash + histogram ----
    const float4* p4 = (const float4*)(pos + (size_t)3 * (size_t)start);
    for (int j4 = tid * 4; j4 < cnt; j4 += TB * 4) {
        int g = j4 >> 2;
        float4 A = p4[3 * g + 0];
        float4 B = p4[3 * g + 1];
        float4 C = p4[3 * g + 2];
        float xs0 = A.x, ys0 = A.y, zs0 = A.z;
        float xs1 = A.w, ys1 = B.x, zs1 = B.y;
        float xs2 = B.z, ys2 = B.w, zs2 = C.x;
        float xs3 = C.y, ys3 = C.z, zs3 = C.w;

        unsigned pv[4];
        #define PROJ(K, PX, PY, PZ)                                          \
        {                                                                    \
            float x = r00 * PX + r01 * PY + r02 * PZ + t0;                   \
            float y = r10 * PX + r11 * PY + r12 * PZ + t1;                   \
            float z = r20 * PX + r21 * PY + r22 * PZ + t2;                   \
            float u = fx * x / z + cx;                                       \
            float v = fy * y / z + cy;                                       \
            int xi = (int)u;   /* trunc == numpy astype(int32) */            \
            int yi = (int)v;                                                 \
            unsigned p = 0xFFFFFFFFu;                                        \
            if (xi >= 0 && xi < IMGW && yi >= 0 && yi < IMGW) {              \
                p = ((unsigned)yi << 10) | (unsigned)xi;                     \
                int tt = ((yi >> 5) << 5) + (xi >> 5);                       \
                atomicAdd(&h[tt], 1u);                                       \
            }                                                                \
            pv[K] = p;                                                       \
        }
        PROJ(0, xs0, ys0, zs0)
        PROJ(1, xs1, ys1, zs1)
        PROJ(2, xs2, ys2, zs2)
        PROJ(3, xs3, ys3, zs3)
        #undef PROJ

        *(uint4*)&stash[j4] = make_uint4(pv[0], pv[1], pv[2], pv[3]);
    }
    __syncthreads();

    // ---- exclusive scan of RAW counts (dense; thread owns tiles 2t,2t+1) --
    unsigned c0 = h[2 * tid];
    unsigned c1 = h[2 * tid + 1];
    unsigned v = c0 + c1;
    sc[tid] = v;
    __syncthreads();
    for (int off = 1; off < TB; off <<= 1) {
        unsigned add = (tid >= off) ? sc[tid - off] : 0u;
        __syncthreads();
        v += add;
        sc[tid] = v;
        __syncthreads();
    }
    base_[2 * tid]     = v - c0 - c1;
    base_[2 * tid + 1] = v - c1;
    __syncthreads();

    // ---- publish (base<<16 | count) TILE-MAJOR; init cursors ----
    for (int t = tid; t < NT; t += TB) {
        cur[t] = base_[t];
        histG[(size_t)t * NB + blockIdx.x] = (base_[t] << 16) | h[t];
    }
    __syncthreads();

    // ---- pass 2: replay stash -> dense stores into private region ----
    unsigned* myRegion = bins + (size_t)blockIdx.x * (size_t)region;
    for (int j = tid; j < cnt; j += TB) {
        unsigned pv = stash[j];
        if (pv == 0xFFFFFFFFu) continue;
        unsigned xi = pv & 1023u, yi = pv >> 10;
        unsigned t  = ((yi >> 5) << 5) + (xi >> 5);
        unsigned lp = ((yi & 31u) << 5) + (xi & 31u);
        unsigned slot = atomicAdd(&cur[t], 1u);         // LDS
        myRegion[slot] = (lp << 22) | (unsigned)(start + j);
    }
}

__global__ void __launch_bounds__(TB)
paint_kernel(const unsigned* __restrict__ bins,
             const unsigned* __restrict__ histG,
             const float* __restrict__ colors,
             float* __restrict__ out,
             int region) {
    __shared__ unsigned win[NT];    // winner index + 1 per local pixel
    int t = blockIdx.x;
    int tid = threadIdx.x;
    win[tid] = 0;
    win[tid + TB] = 0;
    __syncthreads();

    // thread tid owns run (region tid, tile t): exact count, dense
    {
        unsigned pk = histG[(size_t)t * NB + tid];      // coalesced
        unsigned sbase = pk >> 16, cnt = pk & 0xFFFFu;
        const unsigned* seg = bins + (size_t)tid * (size_t)region + sbase;
        for (unsigned k = 0; k < cnt; ++k) {
            unsigned e = seg[k];
            atomicMax(&win[e >> 22], (e & 0x3FFFFFu) + 1u); // LDS
        }
    }
    __syncthreads();

    int tx = (t & 31) << 5, ty = (t >> 5) << 5;
    for (int l = tid; l < NT; l += TB) {
        unsigned w = win[l];
        float r = 0.0f, g = 0.0f, bl = 0.0f;
        if (w) {
            unsigned wi = w - 1u;
            r  = fminf(fmaxf(colors[3 * wi + 0], 0.0f), 1.0f);
            g  = fminf(fmaxf(colors[3 * wi + 1], 0.0f), 1.0f);
            bl = fminf(fmaxf(colors[3 * wi + 2], 0.0f), 1.0f);
        }
        int x = tx + (l & 31), y = ty + (l >> 5);
        int p = y * IMGW + x;
        out[p] = r;
        out[IMGHW + p] = g;
        out[2 * IMGHW + p] = bl;
    }
}

// ---------- fallback: memset + single atomic pass + paint ----------

__global__ void proj_simple(const float* __restrict__ pos,
                            const float* __restrict__ pose,
                            const float* __restrict__ intr,
                            const int* __restrict__ Hp,
                            const int* __restrict__ Wp,
                            int* __restrict__ winner, int n) {
    int i = blockIdx.x * blockDim.x + threadIdx.x;
    if (i >= n) return;
    float px = pos[3 * i], py = pos[3 * i + 1], pz = pos[3 * i + 2];
    float x = pose[0] * px + pose[1] * py + pose[2]  * pz + pose[3];
    float y = pose[4] * px + pose[5] * py + pose[6]  * pz + pose[7];
    float z = pose[8] * px + pose[9] * py + pose[10] * pz + pose[11];
    float u = intr[0] * x / z + intr[2];
    float v = intr[4] * y / z + intr[5];
    int xi = (int)u, yi = (int)v;
    int W = *Wp, H = *Hp;
    if (xi >= 0 && xi < W && yi >= 0 && yi < H) atomicMax(&winner[yi * W + xi], i);
}

__global__ void paint_simple(const int* __restrict__ winner,
                             const float* __restrict__ colors,
                             float* __restrict__ out, int HW) {
    int p = blockIdx.x * blockDim.x + threadIdx.x;
    if (p >= HW) return;
    int w = winner[p];
    float r = 0.0f, g = 0.0f, b = 0.0f;
    if (w >= 0) {
        r = fminf(fmaxf(colors[3 * w + 0], 0.0f), 1.0f);
        g = fminf(fmaxf(colors[3 * w + 1], 0.0f), 1.0f);
        b = fminf(fmaxf(colors[3 * w + 2], 0.0f), 1.0f);
    }
    out[p] = r; out[HW + p] = g; out[2 * HW + p] = b;
}

extern "C" void kernel_launch(void* const* d_in, const int* in_sizes, int n_in,
                              void* d_out, int out_size, void* d_ws, size_t ws_size,
                              hipStream_t stream) {
    const float* positions = (const float*)d_in[0];
    const float* colors    = (const float*)d_in[1];
    const float* pose      = (const float*)d_in[2];
    const float* intr      = (const float*)d_in[3];
    const int*   Hp        = (const int*)d_in[4];
    const int*   Wp        = (const int*)d_in[5];
    float* out = (float*)d_out;

    int n  = in_sizes[0] / 3;       // number of points
    int HW = out_size / 3;          // H*W pixels

    int ppb = ((n + NB - 1) / NB + 3) & ~3;             // multiple of 4
    int region = (int)align8u((unsigned)ppb);           // dense, aligned base
    unsigned* bins  = (unsigned*)d_ws;
    unsigned* histG = bins + (size_t)NB * (size_t)region;
    size_t needFast = ((size_t)NB * region + (size_t)NT * NB) * sizeof(unsigned);

    bool fast = (HW == IMGHW) && (n >= 4096) && ((n & 3) == 0) &&
                (ppb <= PPB_MAX) && (n <= 4000000) && (ws_size >= needFast);

    if (fast) {
        binsort_kernel<<<NB, TB, 0, stream>>>(positions, pose, intr,
                                              bins, histG, n, ppb, region);
        paint_kernel<<<NT, TB, 0, stream>>>(bins, histG, colors, out, region);
        return;
    }

    // ---- fallback ----
    int* winner = (int*)d_ws;
    const int block = 256;
    hipMemsetAsync(winner, 0xFF, (size_t)HW * sizeof(int), stream);
    int grid = (n + block - 1) / block;
    proj_simple<<<grid, block, 0, stream>>>(positions, pose, intr, Hp, Wp,
                                            winner, n);
    int grid2 = (HW + block - 1) / block;
    paint_simple<<<grid2, block, 0, stream>>>(winner, colors, out, HW);
}